// Round 12
// baseline (4847.722 us; speedup 1.0000x reference)
//
#include <hip/hip_runtime.h>
#include <hip/hip_fp16.h>

// LSTM: B=32, T=4096, D=256, H=256, gates=1024 (i,g,f,o), HORIZON=24
// r12 = r11 (int8 dot4 scan) + K-split thread pairing to halve the LDS h-broadcast:
//   thread t: j=t>>1, kh=t&1 owns ALL 4 gates of j over K-half kh (128 i8 dwords).
//   - h reads: 8 uniform-ish b128/wave (2 addrs/wave, 2-way bank alias = free)
//     -> 64 LDS reads/CU/step, half of r11.
//   - K-halves combined with 4 shfl_xor(acc,1) (quad-perm DPP, VALU pipe).
//   - all 4 gates in-thread post-combine -> no gate-crossing shfl; epilogue
//     computed redundantly in both K-half lanes (cheap), kh==0 writes h.
//   - ONE raw barrier/step, parity-dbuf i8 h (512B LDS), G-prefetch in flight.
//   k_prep_w8: one wave per column (shfl-max), fully parallel.

#define T_STEPS 4096
#define BATCH 32

typedef short short8 __attribute__((ext_vector_type(8)));
typedef float f32x4 __attribute__((ext_vector_type(4)));
typedef _Float16 half2_t __attribute__((ext_vector_type(2)));

__device__ inline unsigned short f32_to_bf16(float f) {
  unsigned int u = __builtin_bit_cast(unsigned int, f);
  u = u + 0x7fffu + ((u >> 16) & 1u);   // RNE
  return (unsigned short)(u >> 16);
}

__device__ inline int dot4i8(unsigned int a, unsigned int b, int acc) {
#if __has_builtin(__builtin_amdgcn_sdot4)
  return __builtin_amdgcn_sdot4((int)a, (int)b, acc, false);
#else
  int r = acc;
#pragma unroll
  for (int k = 0; k < 4; ++k) {
    int av = (int)(signed char)((a >> (8 * k)) & 0xff);
    int bv = (int)(signed char)((b >> (8 * k)) & 0xff);
    r += av * bv;
  }
  return r;
#endif
}

// ---------------- prep: x f32 -> bf16 ----------------
__global__ void k_prep_x(const float4* __restrict__ x, unsigned short* __restrict__ xbf, int n4) {
  int i = blockIdx.x * blockDim.x + threadIdx.x;
  if (i >= n4) return;
  float4 v = x[i];
  ushort4 o;
  o.x = f32_to_bf16(v.x); o.y = f32_to_bf16(v.y);
  o.z = f32_to_bf16(v.z); o.w = f32_to_bf16(v.w);
  ((ushort4*)xbf)[i] = o;
}

// ---------------- prep: Wx^T bf16 for xproj ----------------
__global__ void k_prep_wx(const float* __restrict__ W, unsigned short* __restrict__ WxT) {
  int i = blockIdx.x * blockDim.x + threadIdx.x;
  if (i >= 256 * 1024) return;
  int n = i >> 8, k = i & 255;
  WxT[i] = f32_to_bf16(W[k * 1024 + n]);
}

// ---------------- prep: W_h int8 quantization (one WAVE per column) ----------------
// Column c = gate*256 + jj. Lane l (kh=l>>5, p4=l&31) packs k = 4l..4l+3 into one dword.
// Layout: Wq4 as uint[32][512][4]: [p4][t=2*jj+kh][gate]. Scales qs4 float[512][4]: [t][gate].
__global__ __launch_bounds__(512) void k_prep_w8(const float* __restrict__ W,
                                                 unsigned int* __restrict__ Wq4,
                                                 float* __restrict__ qs4) {
  int c = blockIdx.x * 8 + (threadIdx.x >> 6);   // column, 8 waves/block
  int l = threadIdx.x & 63;
  int gate = c >> 8, jj = c & 255;

  float w0 = W[(256 + 4 * l + 0) * 1024 + c];
  float w1 = W[(256 + 4 * l + 1) * 1024 + c];
  float w2 = W[(256 + 4 * l + 2) * 1024 + c];
  float w3 = W[(256 + 4 * l + 3) * 1024 + c];
  float mm = fmaxf(fmaxf(fabsf(w0), fabsf(w1)), fmaxf(fabsf(w2), fabsf(w3)));
#pragma unroll
  for (int s = 32; s; s >>= 1) mm = fmaxf(mm, __shfl_xor(mm, s, 64));
  if (mm < 1e-20f) mm = 1e-20f;
  float inv = 127.0f / mm;

  int q0 = (int)rintf(w0 * inv); q0 = q0 > 127 ? 127 : (q0 < -127 ? -127 : q0);
  int q1 = (int)rintf(w1 * inv); q1 = q1 > 127 ? 127 : (q1 < -127 ? -127 : q1);
  int q2 = (int)rintf(w2 * inv); q2 = q2 > 127 ? 127 : (q2 < -127 ? -127 : q2);
  int q3 = (int)rintf(w3 * inv); q3 = q3 > 127 ? 127 : (q3 < -127 ? -127 : q3);
  unsigned int d = (unsigned int)(q0 & 0xff) | ((unsigned int)(q1 & 0xff) << 8) |
                   ((unsigned int)(q2 & 0xff) << 16) | ((unsigned int)(q3 & 0xff) << 24);

  int kh = l >> 5, p4 = l & 31;
  Wq4[((p4 * 512) + (jj * 2 + kh)) * 4 + gate] = d;
  if (l == 0) {
    float s = mm / (127.0f * 127.0f);
    qs4[(jj * 2 + 0) * 4 + gate] = s;
    qs4[(jj * 2 + 1) * 4 + gate] = s;
  }
}

// ---------------- xproj: gates_x = x @ Wx + b (+1 on f-gate) ----------------
// M=131072, N=1024, K=256. Output layout: G[m][j][gate], gate order (i,g,f,o).
__global__ __launch_bounds__(256) void k_xproj(const unsigned short* __restrict__ A,
                                               const unsigned short* __restrict__ BT,
                                               const float* __restrict__ bias,
                                               __half* __restrict__ G) {
  int bm = blockIdx.x * 64;
  int bn = blockIdx.y * 64;
  int lane = threadIdx.x & 63, wave = threadIdx.x >> 6;
  int wm = (wave & 1) * 32, wn = (wave >> 1) * 32;
  int q = lane >> 4, l16 = lane & 15;

  f32x4 acc[2][2] = {};
  const unsigned short* Ab = A + (size_t)(bm + wm + l16) * 256 + q * 8;
  const unsigned short* Bb = BT + (size_t)(bn + wn + l16) * 256 + q * 8;

#pragma unroll
  for (int kk = 0; kk < 8; ++kk) {
    short8 a0 = *(const short8*)(Ab + kk * 32);
    short8 a1 = *(const short8*)(Ab + 16 * 256 + kk * 32);
    short8 b0 = *(const short8*)(Bb + kk * 32);
    short8 b1 = *(const short8*)(Bb + 16 * 256 + kk * 32);
    acc[0][0] = __builtin_amdgcn_mfma_f32_16x16x32_bf16(a0, b0, acc[0][0], 0, 0, 0);
    acc[0][1] = __builtin_amdgcn_mfma_f32_16x16x32_bf16(a0, b1, acc[0][1], 0, 0, 0);
    acc[1][0] = __builtin_amdgcn_mfma_f32_16x16x32_bf16(a1, b0, acc[1][0], 0, 0, 0);
    acc[1][1] = __builtin_amdgcn_mfma_f32_16x16x32_bf16(a1, b1, acc[1][1], 0, 0, 0);
  }

#pragma unroll
  for (int nt = 0; nt < 2; ++nt) {
    int col = bn + wn + nt * 16 + l16;
    float bv = bias[col] + ((col >= 512 && col < 768) ? 1.0f : 0.0f);
    int gate = col >> 8, jj = col & 255;
#pragma unroll
    for (int mt = 0; mt < 2; ++mt) {
#pragma unroll
      for (int r = 0; r < 4; ++r) {
        int row = bm + wm + mt * 16 + q * 4 + r;
        G[(size_t)row * 1024 + jj * 4 + gate] = __float2half_rn(acc[mt][nt][r] + bv);
      }
    }
  }
}

// ---------------- recurrent scan (int8 dot4, K-split pairs) ----------------
// 32 blocks (1 batch/CU) x 512 threads. Thread t: j=t>>1, kh=t&1.
// Owns all 4 gate-columns of j over k in [kh*128, kh*128+128).
__global__ __launch_bounds__(512, 2) void k_scan(const unsigned int* __restrict__ Wq4,
                                                 const float* __restrict__ qs4,
                                                 const __half* __restrict__ G,
                                                 float* __restrict__ hfin) {
  __shared__ __align__(16) unsigned int h8[2][64];   // h as i8, parity dbuf (256B each)

  int tid = threadIdx.x;
  int b = blockIdx.x;
  int j = tid >> 1;
  int kh = tid & 1;

  // resident i8 weights: 32 k-chunks x 4 gates
  unsigned int wI[32], wG[32], wF[32], wO[32];
  {
    const uint4* wqp = (const uint4*)Wq4;
#pragma unroll
    for (int p4 = 0; p4 < 32; ++p4) {
      uint4 w = wqp[p4 * 512 + tid];
      wI[p4] = w.x; wG[p4] = w.y; wF[p4] = w.z; wO[p4] = w.w;
    }
  }
  float4 sc = *(const float4*)(qs4 + tid * 4);   // dequant scales {i,g,f,o}

  if (tid < 64) h8[0][tid] = 0u;   // h0 = 0
  float cst = 0.0f;                // redundant in both kh lanes (identical arithmetic)

  const unsigned short* gp = (const unsigned short*)G + (size_t)b * T_STEPS * 1024 + j * 4;
  uint2 gx_next = *(const uint2*)gp;   // all 4 gate_x of j (both kh lanes read same)
  __syncthreads();

  for (int step = 0; step < T_STEPS; ++step) {
    uint2 gx_cur = gx_next;
    if (step + 1 < T_STEPS)
      gx_next = *(const uint2*)(gp + (size_t)(step + 1) * 1024);   // stays in flight

    const uint4* hq = (const uint4*)h8[step & 1];

    int aI = 0, aG = 0, aF = 0, aO = 0;
#pragma unroll
    for (int ch = 0; ch < 8; ++ch) {
      uint4 hh = hq[kh * 8 + ch];         // 2 addrs/wave -> 2-way bank alias (free)
      aI = dot4i8(wI[ch * 4 + 0], hh.x, aI); aG = dot4i8(wG[ch * 4 + 0], hh.x, aG);
      aF = dot4i8(wF[ch * 4 + 0], hh.x, aF); aO = dot4i8(wO[ch * 4 + 0], hh.x, aO);
      aI = dot4i8(wI[ch * 4 + 1], hh.y, aI); aG = dot4i8(wG[ch * 4 + 1], hh.y, aG);
      aF = dot4i8(wF[ch * 4 + 1], hh.y, aF); aO = dot4i8(wO[ch * 4 + 1], hh.y, aO);
      aI = dot4i8(wI[ch * 4 + 2], hh.z, aI); aG = dot4i8(wG[ch * 4 + 2], hh.z, aG);
      aF = dot4i8(wF[ch * 4 + 2], hh.z, aF); aO = dot4i8(wO[ch * 4 + 2], hh.z, aO);
      aI = dot4i8(wI[ch * 4 + 3], hh.w, aI); aG = dot4i8(wG[ch * 4 + 3], hh.w, aG);
      aF = dot4i8(wF[ch * 4 + 3], hh.w, aF); aO = dot4i8(wO[ch * 4 + 3], hh.w, aO);
    }

    // combine K-halves across the lane pair (xor-1 = quad-perm DPP, VALU pipe)
    aI += __shfl_xor(aI, 1, 64);
    aG += __shfl_xor(aG, 1, 64);
    aF += __shfl_xor(aF, 1, 64);
    aO += __shfl_xor(aO, 1, 64);

    // dequant + gates_x; epilogue redundantly in both kh lanes
    half2_t g01 = __builtin_bit_cast(half2_t, gx_cur.x);   // (i, g)
    half2_t g23 = __builtin_bit_cast(half2_t, gx_cur.y);   // (f, o)  (+1 folded on f)
    float gi = (float)aI * sc.x + (float)g01.x;
    float gg = (float)aG * sc.y + (float)g01.y;
    float gf = (float)aF * sc.z + (float)g23.x;
    float go = (float)aO * sc.w + (float)g23.y;

    float si = 1.0f / (1.0f + __expf(-gi));
    float sf = 1.0f / (1.0f + __expf(-gf));
    float so = 1.0f / (1.0f + __expf(-go));
    float eg = __expf(2.0f * gg);
    float tg = 1.0f - 2.0f / (eg + 1.0f);      // tanh(g), overflow-safe
    cst = sf * cst + si * tg;
    float ec = __expf(2.0f * cst);
    float tc = 1.0f - 2.0f / (ec + 1.0f);
    float h = so * tc;                         // |h| < 1 strictly

    if (!kh) {
      int hi = (int)rintf(h * 127.0f);
      ((char*)h8[(step + 1) & 1])[j] = (char)hi;     // ds_write_b8, per-lane distinct
      if (step == T_STEPS - 1) hfin[b * 256 + j] = h;
    }

    // ONE raw barrier: drain LDS (h8 writes); G-prefetch stays in flight
    asm volatile("s_waitcnt lgkmcnt(0)\n\ts_barrier" ::: "memory");
  }
}

// ---------------- head: out = (h@Wfc+bfc)@Wout+bout ----------------
__global__ void k_head(const float* __restrict__ hfin, const float* __restrict__ Wfc,
                       const float* __restrict__ bfc, const float* __restrict__ Wout,
                       const float* __restrict__ bout, float* __restrict__ out) {
  __shared__ float hs[256];
  __shared__ float fcs[256];
  int b = blockIdx.x, j = threadIdx.x;
  hs[j] = hfin[b * 256 + j];
  __syncthreads();
  float acc = bfc[j];
#pragma unroll 8
  for (int k = 0; k < 256; ++k) acc += hs[k] * Wfc[k * 256 + j];
  fcs[j] = acc;
  __syncthreads();
  if (j < 24) {
    float a2 = bout[j];
#pragma unroll 8
    for (int k = 0; k < 256; ++k) a2 += fcs[k] * Wout[k * 24 + j];
    out[b * 24 + j] = a2;
  }
}

extern "C" void kernel_launch(void* const* d_in, const int* in_sizes, int n_in,
                              void* d_out, int out_size, void* d_ws, size_t ws_size,
                              hipStream_t stream) {
  const float* x    = (const float*)d_in[0];
  const float* Wl   = (const float*)d_in[1];
  const float* bl   = (const float*)d_in[2];
  const float* Wfc  = (const float*)d_in[3];
  const float* bfc  = (const float*)d_in[4];
  const float* Wout = (const float*)d_in[5];
  const float* bout = (const float*)d_in[6];
  float* out = (float*)d_out;

  char* ws = (char*)d_ws;
  // ws layout (bytes), total ~321 MB
  unsigned short* xbf = (unsigned short*)ws;                    //  67108864  x as bf16
  unsigned short* WxT = (unsigned short*)(ws + 67108864);       //    524288  Wx^T bf16 [1024][256]
  unsigned int*   Wq4 = (unsigned int*)(ws + 67633152);         //    262144  Wh i8 [32][512][4]
  float*          qsb = (float*)(ws + 67895296);                //      8192  dequant scales [512][4]
  __half*         G   = (__half*)(ws + 68157440);               // 268435456  gates_x f16 [m][j][gate]
  float*          hfin= (float*)(ws + 336592896);               //     32768  final h f32

  k_prep_x<<<32768, 256, 0, stream>>>((const float4*)x, xbf, 8388608);
  k_prep_wx<<<1024, 256, 0, stream>>>(Wl, WxT);
  k_prep_w8<<<128, 512, 0, stream>>>(Wl, Wq4, qsb);
  dim3 gx(2048, 16, 1);
  k_xproj<<<gx, 256, 0, stream>>>(xbf, WxT, bl, G);
  k_scan<<<32, 512, 0, stream>>>(Wq4, qsb, G, hfin);
  k_head<<<32, 256, 0, stream>>>(hfin, Wfc, bfc, Wout, bout, out);
}

// Round 13
// 4552.184 us; speedup vs baseline: 1.0649x; 1.0649x over previous
//
#include <hip/hip_runtime.h>
#include <hip/hip_fp16.h>

// LSTM: B=32, T=4096, D=256, H=256, gates=1024 (i,g,f,o), HORIZON=24
// r13 = r11 scan (proven 3900us, int8 dot4, 128 dwords W resident, (i,g)/(f,o)
//       lane pairing, ONE raw barrier/step) reverted verbatim (r12's K-split
//       regressed: LDS not binding, VALU 1:1 on critical path)
//     + xproj rebuilt tall-skinny: 64Mx256N block (grid 2048x4), wave = 64x64 out,
//       acc[4][4], 128 MFMA/wave (was 32), A re-read 16x -> 4x, B L2-resident.
//     + parallel prep_w8 (one wave per column, shfl-max) in r11 layout.

#define T_STEPS 4096
#define BATCH 32

typedef short short8 __attribute__((ext_vector_type(8)));
typedef float f32x4 __attribute__((ext_vector_type(4)));
typedef _Float16 half2_t __attribute__((ext_vector_type(2)));

__device__ inline unsigned short f32_to_bf16(float f) {
  unsigned int u = __builtin_bit_cast(unsigned int, f);
  u = u + 0x7fffu + ((u >> 16) & 1u);   // RNE
  return (unsigned short)(u >> 16);
}

__device__ inline int dot4i8(unsigned int a, unsigned int b, int acc) {
#if __has_builtin(__builtin_amdgcn_sdot4)
  return __builtin_amdgcn_sdot4((int)a, (int)b, acc, false);
#else
  int r = acc;
#pragma unroll
  for (int k = 0; k < 4; ++k) {
    int av = (int)(signed char)((a >> (8 * k)) & 0xff);
    int bv = (int)(signed char)((b >> (8 * k)) & 0xff);
    r += av * bv;
  }
  return r;
#endif
}

// ---------------- prep: x f32 -> bf16 ----------------
__global__ void k_prep_x(const float4* __restrict__ x, unsigned short* __restrict__ xbf, int n4) {
  int i = blockIdx.x * blockDim.x + threadIdx.x;
  if (i >= n4) return;
  float4 v = x[i];
  ushort4 o;
  o.x = f32_to_bf16(v.x); o.y = f32_to_bf16(v.y);
  o.z = f32_to_bf16(v.z); o.w = f32_to_bf16(v.w);
  ((ushort4*)xbf)[i] = o;
}

// ---------------- prep: Wx^T bf16 for xproj ----------------
__global__ void k_prep_wx(const float* __restrict__ W, unsigned short* __restrict__ WxT) {
  int i = blockIdx.x * blockDim.x + threadIdx.x;
  if (i >= 256 * 1024) return;
  int n = i >> 8, k = i & 255;
  WxT[i] = f32_to_bf16(W[k * 1024 + n]);
}

// ---------------- prep: W_h int8 quantization (one WAVE per column, r11 layout) ----------------
// Column c; lane l packs k = 4l..4l+3 into one dword (p4 = l). Per-column scale via shfl-max.
// r11 pairing: c<256 (i): t=2c,slot0 ; c<512 (g): t=2(c-256),slot1 ;
//              c<768 (f): t=2(c-512)+1,slot0 ; else (o): t=2(c-768)+1,slot1.
// Wq8[p4*1024 + t*2 + slot] ; qs[t*2+slot] = m/127^2.
__global__ __launch_bounds__(512) void k_prep_w8(const float* __restrict__ W,
                                                 unsigned int* __restrict__ Wq8,
                                                 float* __restrict__ qs) {
  int c = blockIdx.x * 8 + (threadIdx.x >> 6);
  int l = threadIdx.x & 63;

  float w0 = W[(256 + 4 * l + 0) * 1024 + c];
  float w1 = W[(256 + 4 * l + 1) * 1024 + c];
  float w2 = W[(256 + 4 * l + 2) * 1024 + c];
  float w3 = W[(256 + 4 * l + 3) * 1024 + c];
  float mm = fmaxf(fmaxf(fabsf(w0), fabsf(w1)), fmaxf(fabsf(w2), fabsf(w3)));
#pragma unroll
  for (int s = 32; s; s >>= 1) mm = fmaxf(mm, __shfl_xor(mm, s, 64));
  if (mm < 1e-20f) mm = 1e-20f;
  float inv = 127.0f / mm;

  int q0 = (int)rintf(w0 * inv); q0 = q0 > 127 ? 127 : (q0 < -127 ? -127 : q0);
  int q1 = (int)rintf(w1 * inv); q1 = q1 > 127 ? 127 : (q1 < -127 ? -127 : q1);
  int q2 = (int)rintf(w2 * inv); q2 = q2 > 127 ? 127 : (q2 < -127 ? -127 : q2);
  int q3 = (int)rintf(w3 * inv); q3 = q3 > 127 ? 127 : (q3 < -127 ? -127 : q3);
  unsigned int d = (unsigned int)(q0 & 0xff) | ((unsigned int)(q1 & 0xff) << 8) |
                   ((unsigned int)(q2 & 0xff) << 16) | ((unsigned int)(q3 & 0xff) << 24);

  int t, slot;
  if (c < 256)      { t = 2 * c;             slot = 0; }
  else if (c < 512) { t = 2 * (c - 256);     slot = 1; }
  else if (c < 768) { t = 2 * (c - 512) + 1; slot = 0; }
  else              { t = 2 * (c - 768) + 1; slot = 1; }
  Wq8[l * 1024 + t * 2 + slot] = d;
  if (l == 0) qs[t * 2 + slot] = mm / (127.0f * 127.0f);
}

// ---------------- xproj: gates_x = x @ Wx + b (+1 on f-gate) ----------------
// M=131072, N=1024, K=256. Tall-skinny: block = 64M x 256N (grid 2048x4, 256thr);
// wave w owns N-span w*64. acc[4][4], 128 MFMA/wave. Output G[m][j][gate] f16.
__global__ __launch_bounds__(256) void k_xproj(const unsigned short* __restrict__ A,
                                               const unsigned short* __restrict__ BT,
                                               const float* __restrict__ bias,
                                               __half* __restrict__ G) {
  int bm = blockIdx.x * 64;
  int bn = blockIdx.y * 256;
  int lane = threadIdx.x & 63, wave = threadIdx.x >> 6;
  int wn = wave * 64;
  int q = lane >> 4, l16 = lane & 15;

  f32x4 acc[4][4] = {};
  const unsigned short* Ab = A + (size_t)(bm + l16) * 256 + q * 8;
  const unsigned short* Bb = BT + (size_t)(bn + wn + l16) * 256 + q * 8;

#pragma unroll
  for (int kk = 0; kk < 8; ++kk) {
    short8 a[4], bf[4];
#pragma unroll
    for (int mt = 0; mt < 4; ++mt) a[mt] = *(const short8*)(Ab + mt * 16 * 256 + kk * 32);
#pragma unroll
    for (int nt = 0; nt < 4; ++nt) bf[nt] = *(const short8*)(Bb + nt * 16 * 256 + kk * 32);
#pragma unroll
    for (int mt = 0; mt < 4; ++mt)
#pragma unroll
      for (int nt = 0; nt < 4; ++nt)
        acc[mt][nt] = __builtin_amdgcn_mfma_f32_16x16x32_bf16(a[mt], bf[nt], acc[mt][nt], 0, 0, 0);
  }

#pragma unroll
  for (int nt = 0; nt < 4; ++nt) {
    int col = bn + wn + nt * 16 + l16;
    float bv = bias[col] + ((col >= 512 && col < 768) ? 1.0f : 0.0f);
    int gate = col >> 8, jj = col & 255;
#pragma unroll
    for (int mt = 0; mt < 4; ++mt) {
#pragma unroll
      for (int r = 0; r < 4; ++r) {
        int row = bm + mt * 16 + q * 4 + r;
        G[(size_t)row * 1024 + jj * 4 + gate] = __float2half_rn(acc[mt][nt][r] + bv);
      }
    }
  }
}

// ---------------- recurrent scan (int8 dot4) — r11 verbatim ----------------
// 32 blocks (1 batch/CU) x 512 threads. Thread t: j=t>>1; even->(i,g), odd->(f,o).
// W_h: 128 dwords/thread fully register-resident. h: i8[256] in LDS (512B,
// parity dbuf), read as 16 uniform b128/wave.
__global__ __launch_bounds__(512, 2) void k_scan(const uint2* __restrict__ Wq8,
                                                 const float2* __restrict__ qs,
                                                 const __half* __restrict__ G,
                                                 float* __restrict__ hfin) {
  __shared__ __align__(16) unsigned int h8[2][64];   // h as i8, parity dbuf

  int tid = threadIdx.x;
  int b = blockIdx.x;
  int j = tid >> 1;
  int odd = tid & 1;

  // resident i8 weights: 64 dwords per column x 2 columns
  unsigned int wA[64], wB[64];
#pragma unroll
  for (int p4 = 0; p4 < 64; ++p4) {
    uint2 w = Wq8[p4 * 512 + tid];
    wA[p4] = w.x; wB[p4] = w.y;
  }
  float2 sc = qs[tid];   // dequant scales {A, B}

  if (tid < 64) { h8[0][tid] = 0u; }
  float cst = 0.0f;      // lives in odd lanes

  const unsigned short* gp = (const unsigned short*)G + (size_t)b * T_STEPS * 1024 + j * 4 + odd * 2;
  unsigned int gx_next = *(const unsigned int*)gp;
  __syncthreads();

  for (int step = 0; step < T_STEPS; ++step) {
    unsigned int gx_cur = gx_next;
    if (step + 1 < T_STEPS)
      gx_next = *(const unsigned int*)(gp + (size_t)(step + 1) * 1024);   // stays in flight

    const uint4* hq = (const uint4*)h8[step & 1];

    int accA0 = 0, accB0 = 0, accA1 = 0, accB1 = 0;   // 2 chains per column
#pragma unroll
    for (int ch = 0; ch < 16; ++ch) {
      uint4 hh = hq[ch];
      accA0 = dot4i8(wA[ch * 4 + 0], hh.x, accA0); accB0 = dot4i8(wB[ch * 4 + 0], hh.x, accB0);
      accA1 = dot4i8(wA[ch * 4 + 1], hh.y, accA1); accB1 = dot4i8(wB[ch * 4 + 1], hh.y, accB1);
      accA0 = dot4i8(wA[ch * 4 + 2], hh.z, accA0); accB0 = dot4i8(wB[ch * 4 + 2], hh.z, accB0);
      accA1 = dot4i8(wA[ch * 4 + 3], hh.w, accA1); accB1 = dot4i8(wB[ch * 4 + 3], hh.w, accB1);
    }

    // dequant + add gates_x
    half2_t gxh = __builtin_bit_cast(half2_t, gx_cur);
    float Av = (float)(accA0 + accA1) * sc.x + (float)gxh.x;   // even: i ; odd: f (+1 folded)
    float Bv = (float)(accB0 + accB1) * sc.y + (float)gxh.y;   // even: g ; odd: o

    // epilogue: cross (i,g)->(f,o) lane via shfl_xor(1)
    float sA = 1.0f / (1.0f + __expf(-Av));            // si | sf
    float eB = __expf(2.0f * Bv);
    float tB = 1.0f - 2.0f / (eB + 1.0f);              // tanh(g) | (unused)
    float a = sA * tB;
    float a_x = __shfl_xor(a, 1, 64);
    if (odd) {
      float so = 1.0f / (1.0f + __expf(-Bv));
      cst = sA * cst + a_x;                            // c = sf*c + si*tanh(g)
      float ec = __expf(2.0f * cst);
      float tc = 1.0f - 2.0f / (ec + 1.0f);
      float h = so * tc;                               // |h| < 1 strictly
      int hi = (int)rintf(h * 127.0f);
      ((char*)h8[(step + 1) & 1])[j] = (char)hi;       // ds_write_b8
      if (step == T_STEPS - 1) hfin[b * 256 + j] = h;
    }

    // ONE raw barrier: drain LDS (h8 writes); G-prefetch stays in flight
    asm volatile("s_waitcnt lgkmcnt(0)\n\ts_barrier" ::: "memory");
  }
}

// ---------------- head: out = (h@Wfc+bfc)@Wout+bout ----------------
__global__ void k_head(const float* __restrict__ hfin, const float* __restrict__ Wfc,
                       const float* __restrict__ bfc, const float* __restrict__ Wout,
                       const float* __restrict__ bout, float* __restrict__ out) {
  __shared__ float hs[256];
  __shared__ float fcs[256];
  int b = blockIdx.x, j = threadIdx.x;
  hs[j] = hfin[b * 256 + j];
  __syncthreads();
  float acc = bfc[j];
#pragma unroll 8
  for (int k = 0; k < 256; ++k) acc += hs[k] * Wfc[k * 256 + j];
  fcs[j] = acc;
  __syncthreads();
  if (j < 24) {
    float a2 = bout[j];
#pragma unroll 8
    for (int k = 0; k < 256; ++k) a2 += fcs[k] * Wout[k * 24 + j];
    out[b * 24 + j] = a2;
  }
}

extern "C" void kernel_launch(void* const* d_in, const int* in_sizes, int n_in,
                              void* d_out, int out_size, void* d_ws, size_t ws_size,
                              hipStream_t stream) {
  const float* x    = (const float*)d_in[0];
  const float* Wl   = (const float*)d_in[1];
  const float* bl   = (const float*)d_in[2];
  const float* Wfc  = (const float*)d_in[3];
  const float* bfc  = (const float*)d_in[4];
  const float* Wout = (const float*)d_in[5];
  const float* bout = (const float*)d_in[6];
  float* out = (float*)d_out;

  char* ws = (char*)d_ws;
  // ws layout (bytes), total ~321 MB
  unsigned short* xbf = (unsigned short*)ws;                    //  67108864  x as bf16
  unsigned short* WxT = (unsigned short*)(ws + 67108864);       //    524288  Wx^T bf16 [1024][256]
  unsigned int*   Wq8 = (unsigned int*)(ws + 67633152);         //    262144  Wh i8 [64][512][2]
  float*          qsb = (float*)(ws + 67895296);                //      4096  dequant scales [512][2]
  __half*         G   = (__half*)(ws + 68157440);               // 268435456  gates_x f16 [m][j][gate]
  float*          hfin= (float*)(ws + 336592896);               //     32768  final h f32

  k_prep_x<<<32768, 256, 0, stream>>>((const float4*)x, xbf, 8388608);
  k_prep_wx<<<1024, 256, 0, stream>>>(Wl, WxT);
  k_prep_w8<<<128, 512, 0, stream>>>(Wl, Wq8, qsb);
  dim3 gx(2048, 4, 1);
  k_xproj<<<gx, 256, 0, stream>>>(xbf, WxT, bl, G);
  k_scan<<<32, 512, 0, stream>>>((const uint2*)Wq8, (const float2*)qsb, G, hfin);
  k_head<<<32, 256, 0, stream>>>(hfin, Wfc, bfc, Wout, bout, out);
}